// Round 13
// baseline (240.203 us; speedup 1.0000x reference)
//
#include <hip/hip_runtime.h>
#include <hip/hip_bf16.h>
#include <cstdint>

#define D_MODEL 2048
#define N_BATCH 16384

typedef __attribute__((ext_vector_type(8))) __bf16 bf16x8;
typedef __attribute__((ext_vector_type(4))) float f32x4;

__device__ __forceinline__ unsigned short f2bf(float f) {
    unsigned int u = __builtin_bit_cast(unsigned int, f);
    u += 0x7fffu + ((u >> 16) & 1u);
    return (unsigned short)(u >> 16);
}

// ============ K1: fused prep = transpose(w_v) || convert(w_o) || bias ============
__global__ __launch_bounds__(256) void prep_kernel(
    const float* __restrict__ w_v, const float* __restrict__ w_o,
    const float* __restrict__ b_v, const float* __restrict__ b_o,
    unsigned short* __restrict__ wvT, unsigned short* __restrict__ woB,
    float* __restrict__ b_c)
{
    __shared__ float tile[32][33];
    const int b = blockIdx.x;
    const int t = threadIdx.x;
    if (b < 4096) {
        const int nb = 64;
        const int k0 = (b % nb) * 32;
        const int j0 = (b / nb) * 32;
        const int tx = t & 31, ty0 = t >> 5;
        #pragma unroll
        for (int i = 0; i < 32; i += 8) {
            int j = ty0 + i;
            tile[j][tx] = w_v[(long)(j0 + j) * D_MODEL + k0 + tx];
        }
        __syncthreads();
        #pragma unroll
        for (int i = 0; i < 32; i += 8) {
            int kk = ty0 + i;
            wvT[(long)(k0 + kk) * D_MODEL + j0 + tx] = f2bf(tile[tx][kk]);
        }
    } else if (b < 6144) {
        long i = ((long)(b - 4096) * 256 + t) * 8;
        const float4* in4 = reinterpret_cast<const float4*>(w_o + i);
        float4 a = in4[0], bb = in4[1];
        union { unsigned short u[8]; uint4 v; } o;
        o.u[0] = f2bf(a.x); o.u[1] = f2bf(a.y); o.u[2] = f2bf(a.z); o.u[3] = f2bf(a.w);
        o.u[4] = f2bf(bb.x); o.u[5] = f2bf(bb.y); o.u[6] = f2bf(bb.z); o.u[7] = f2bf(bb.w);
        *reinterpret_cast<uint4*>(woB + i) = o.v;
    } else {
        const int n = b - 6144;
        const float4* w4 = reinterpret_cast<const float4*>(w_o + (long)n * D_MODEL);
        const float4* v4 = reinterpret_cast<const float4*>(b_v);
        float4 a = w4[t], bb = w4[256 + t], va = v4[t], vb = v4[256 + t];
        float s = a.x*va.x + a.y*va.y + a.z*va.z + a.w*va.w
                + bb.x*vb.x + bb.y*vb.y + bb.z*vb.z + bb.w*vb.w;
        #pragma unroll
        for (int off = 32; off; off >>= 1) s += __shfl_xor(s, off);
        float* red = &tile[0][0];
        const int lane = t & 63, wid = t >> 6;
        if (lane == 0) red[wid] = s;
        __syncthreads();
        if (t == 0) b_c[n] = red[0] + red[1] + red[2] + red[3] + b_o[n];
    }
}

// ============ K2: fused Wc-GEMM (128-tile m97) || LayerNorm ============
__global__ __launch_bounds__(256) void lnwc_kernel(
    const unsigned short* __restrict__ A, const unsigned short* __restrict__ B,
    unsigned short* __restrict__ C,
    const float* __restrict__ x, const float* __restrict__ gamma,
    const float* __restrict__ beta, unsigned short* __restrict__ h)
{
    __shared__ __align__(16) unsigned short Alds[128 * 32];
    __shared__ __align__(16) unsigned short Blds[128 * 32];
    const int t = threadIdx.x;

    if (blockIdx.x < 256) {
        const int K = D_MODEL, N = D_MODEL;
        int wg = blockIdx.x;
        wg = (wg & 7) * 32 + (wg >> 3);         // XCD swizzle, cpx = 32
        const int bm = wg >> 4, bn = wg & 15;

        const int lane = t & 63, wid = t >> 6;
        const int wr = wid >> 1, wc = wid & 1;

        f32x4 acc[4][4];
        #pragma unroll
        for (int i = 0; i < 4; i++)
            #pragma unroll
            for (int j = 0; j < 4; j++) acc[i][j] = (f32x4){0.f, 0.f, 0.f, 0.f};

        const long Abase = (long)bm * 128 * K;
        const long Bbase = (long)bn * 128 * K;
        const int ci0 = wid * 64 + lane;
        const int ci1 = 256 + ci0;
        const int r0 = ci0 >> 2, c0 = (ci0 & 3) * 8;
        const int r1 = ci1 >> 2, c1 = (ci1 & 3) * 8;

        const int arow = wr * 64 + (lane & 15);
        const int brow = wc * 64 + (lane & 15);
        const int koff = (lane >> 4) * 8;

        for (int k0 = 0; k0 < K; k0 += 32) {
            __builtin_amdgcn_global_load_lds(
                (const __attribute__((address_space(1))) void*)(A + Abase + (long)r0 * K + k0 + c0),
                (__attribute__((address_space(3))) void*)(Alds + wid * 512), 16, 0, 0);
            __builtin_amdgcn_global_load_lds(
                (const __attribute__((address_space(1))) void*)(A + Abase + (long)r1 * K + k0 + c1),
                (__attribute__((address_space(3))) void*)(Alds + 2048 + wid * 512), 16, 0, 0);
            __builtin_amdgcn_global_load_lds(
                (const __attribute__((address_space(1))) void*)(B + Bbase + (long)r0 * K + k0 + c0),
                (__attribute__((address_space(3))) void*)(Blds + wid * 512), 16, 0, 0);
            __builtin_amdgcn_global_load_lds(
                (const __attribute__((address_space(1))) void*)(B + Bbase + (long)r1 * K + k0 + c1),
                (__attribute__((address_space(3))) void*)(Blds + 2048 + wid * 512), 16, 0, 0);
            __syncthreads();

            bf16x8 af[4], bfr[4];
            #pragma unroll
            for (int m = 0; m < 4; m++)
                af[m] = *reinterpret_cast<const bf16x8*>(&Alds[(arow + m * 16) * 32 + koff]);
            #pragma unroll
            for (int n = 0; n < 4; n++)
                bfr[n] = *reinterpret_cast<const bf16x8*>(&Blds[(brow + n * 16) * 32 + koff]);
            #pragma unroll
            for (int m = 0; m < 4; m++)
                #pragma unroll
                for (int n = 0; n < 4; n++)
                    acc[m][n] = __builtin_amdgcn_mfma_f32_16x16x32_bf16(af[m], bfr[n], acc[m][n], 0, 0, 0);
            __syncthreads();
        }

        const int crow0 = bm * 128 + wr * 64 + ((lane >> 4) << 2);
        const int ccol0 = bn * 128 + wc * 64 + (lane & 15);
        #pragma unroll
        for (int m = 0; m < 4; m++)
            #pragma unroll
            for (int j = 0; j < 4; j++) {
                const long r = crow0 + m * 16 + j;
                #pragma unroll
                for (int n = 0; n < 4; n++)
                    C[r * N + ccol0 + n * 16] = f2bf(acc[m][n][j]);
            }
    } else {
        const int row = blockIdx.x - 256;
        const float4* x4 = reinterpret_cast<const float4*>(x + (long)row * D_MODEL);
        float4 a = x4[t];
        float4 b = x4[256 + t];
        float s  = a.x + a.y + a.z + a.w + b.x + b.y + b.z + b.w;
        float ss = a.x*a.x + a.y*a.y + a.z*a.z + a.w*a.w
                 + b.x*b.x + b.y*b.y + b.z*b.z + b.w*b.w;
        #pragma unroll
        for (int off = 32; off; off >>= 1) {
            s  += __shfl_xor(s, off);
            ss += __shfl_xor(ss, off);
        }
        float* red = reinterpret_cast<float*>(Alds);
        const int lane = t & 63, wid = t >> 6;
        if (lane == 0) { red[wid*2] = s; red[wid*2+1] = ss; }
        __syncthreads();
        s  = red[0] + red[2] + red[4] + red[6];
        ss = red[1] + red[3] + red[5] + red[7];
        const float mean = s * (1.0f / D_MODEL);
        const float var  = ss * (1.0f / D_MODEL) - mean * mean;
        const float inv  = rsqrtf(var + 1e-5f);

        const float4* g4  = reinterpret_cast<const float4*>(gamma);
        const float4* be4 = reinterpret_cast<const float4*>(beta);
        ushort4* h4 = reinterpret_cast<ushort4*>(h + (long)row * D_MODEL);
        {
            float4 g = g4[t], be = be4[t];
            ushort4 o;
            o.x = f2bf((a.x - mean) * inv * g.x + be.x);
            o.y = f2bf((a.y - mean) * inv * g.y + be.y);
            o.z = f2bf((a.z - mean) * inv * g.z + be.z);
            o.w = f2bf((a.w - mean) * inv * g.w + be.w);
            h4[t] = o;
        }
        {
            float4 g = g4[256 + t], be = be4[256 + t];
            ushort4 o;
            o.x = f2bf((b.x - mean) * inv * g.x + be.x);
            o.y = f2bf((b.y - mean) * inv * g.y + be.y);
            o.z = f2bf((b.z - mean) * inv * g.z + be.z);
            o.w = f2bf((b.w - mean) * inv * g.w + be.w);
            h4[256 + t] = o;
        }
    }
}

// ======== K3: big BT-GEMM, 128x128 tile, BK=64, 2 blocks/CU co-resident ========
// C[m][n] = sum_k A[m][k]*B[n][k] + bias[n] + resid[m][n], fp32 out.
// r13 theory: 1-block/CU lockstep + exposed epilogue was the invariant across
// 8 null schedule variants.  This kernel: 64 KiB LDS -> 2 independent blocks
// per CU (epilogue of one overlaps K-loop of the other; barriers sync only 4
// waves), 128^2 tile = the structure-matched choice for a relaxed loop (m103:
// 912 TF).  Counted vmcnt(8) double-buffer: stage tile kt+1 at top of iter kt
// (WAR-safe: that buffer's reads closed by iter kt-1's end barrier), wait
// vmcnt(8) -> tile kt resident, kt+1's 8 loads stay in flight.  Never 0
// mid-loop.  4 waves (2x2), 64x64/wave, acc[4][4] = 64 AGPR, no spill at
// __launch_bounds__(256,2).
// Swizzle (r2-family, 0-conflict proven): row r (128 B = 8 slots), slot s
// holds k-chunk s^(r&7); staged linear-dst + inverse-swizzled source
// (rule 21); read chunk = (kk*4+l4) ^ (l15&7) -> per 8-lane service group a
// perfect 8-slot permutation.
#define GLL(src, dst) __builtin_amdgcn_global_load_lds( \
    (const __attribute__((address_space(1))) void*)(src), \
    (__attribute__((address_space(3))) void*)(dst), 16, 0, 0)

__global__ __launch_bounds__(256, 2) void gemm_bt_128r(
    const unsigned short* __restrict__ A, const unsigned short* __restrict__ B,
    float* __restrict__ C, const float* __restrict__ bias,
    const float* __restrict__ resid, int M, int N, int K)
{
    __shared__ __align__(16) char ldsb[65536];   // 2 buf x [A 16K | B 16K]

    const int nBN = N >> 7;             // 16
    int wg = blockIdx.x;
    const int cpx = gridDim.x >> 3;     // 2048 % 8 == 0 -> 256
    wg = (wg & 7) * cpx + (wg >> 3);
    const int bm = wg / nBN, bn = wg % nBN;

    const int t = threadIdx.x;
    const int lane = t & 63, wid = t >> 6;
    const int wr = wid >> 1, wc = wid & 1;

    // ---- staging (inverse-swizzled source; 4 row-rounds per operand) ----
    // round rnd covers rows rnd*32 + (t>>3); slot sl = t&7; dst byte =
    // rnd*4096 + t*16 (row*128 + sl*16).  row&7 == (t>>3)&7 for all rnd.
    const long Kl = K;
    const int tr = t >> 3;                                  // 0..31
    const int chA = ((t & 7) ^ (tr & 7)) * 8;               // source k-chunk
    const unsigned short* As = A + (long)(bm * 128 + tr) * Kl + chA;
    const unsigned short* Bs = B + (long)(bn * 128 + tr) * Kl + chA;

#define STAGE(buf, kcol) do { \
    char* da_ = ldsb + (buf) * 32768 + t * 16; \
    char* db_ = da_ + 16384; \
    _Pragma("unroll") for (int rnd = 0; rnd < 4; ++rnd) \
        GLL(As + (long)(rnd * 32) * Kl + (kcol), da_ + rnd * 4096); \
    _Pragma("unroll") for (int rnd = 0; rnd < 4; ++rnd) \
        GLL(Bs + (long)(rnd * 32) * Kl + (kcol), db_ + rnd * 4096); } while (0)

    // ---- ds_read addressing (swizzled) ----
    const int l15 = lane & 15, l4 = lane >> 4;
    const int swz0 = (((0 + l4) ^ (l15 & 7)) << 4);         // kk=0 chunks 0..3
    const int swz1 = (((4 + l4) ^ (l15 & 7)) << 4);         // kk=1 chunks 4..7
    const int aRow = (wr * 64 + l15) * 128;                 // + mi*2048
    const int bRow = 16384 + (wc * 64 + l15) * 128;         // + nj*2048

#define LDV(off) (*reinterpret_cast<const bf16x8*>(ldsb + (off)))

    f32x4 acc[4][4];
    #pragma unroll
    for (int i = 0; i < 4; i++)
        #pragma unroll
        for (int j = 0; j < 4; j++) acc[i][j] = (f32x4){0.f, 0.f, 0.f, 0.f};

    const int nt = K >> 6;              // 32 K-steps
    STAGE(0, 0);                        // prologue: tile 0 -> buf0

    int buf = 0;
    for (int kt = 0; kt < nt; ++kt) {
        if (kt + 1 < nt) {
            STAGE(buf ^ 1, (kt + 1) << 6);   // WAR-safe: closed by prev end-bar
            asm volatile("s_waitcnt vmcnt(8)" ::: "memory");
        } else {
            asm volatile("s_waitcnt vmcnt(0)" ::: "memory");
        }
        __builtin_amdgcn_sched_barrier(0);
        __builtin_amdgcn_s_barrier();        // publish tile kt

        const int bb = buf * 32768;
        bf16x8 af[4][2], bfr[4][2];
        #pragma unroll
        for (int mi = 0; mi < 4; ++mi) {
            af[mi][0] = LDV(bb + aRow + mi * 2048 + swz0);
            af[mi][1] = LDV(bb + aRow + mi * 2048 + swz1);
        }
        #pragma unroll
        for (int nj = 0; nj < 4; ++nj) {
            bfr[nj][0] = LDV(bb + bRow + nj * 2048 + swz0);
            bfr[nj][1] = LDV(bb + bRow + nj * 2048 + swz1);
        }
        #pragma unroll
        for (int kk = 0; kk < 2; ++kk)
            #pragma unroll
            for (int mi = 0; mi < 4; ++mi)
                #pragma unroll
                for (int nj = 0; nj < 4; ++nj)
                    acc[mi][nj] = __builtin_amdgcn_mfma_f32_16x16x32_bf16(
                        af[mi][kk], bfr[nj][kk], acc[mi][nj], 0, 0, 0);

        __builtin_amdgcn_s_barrier();        // close read window for buf
        buf ^= 1;
    }
#undef STAGE
#undef LDV

    // ---- epilogue: C = acc + bias[col] + resid[row][col] ----
    // Overlapped by the co-resident block's K-loop (the r13 point).
    const int crow0 = bm * 128 + wr * 64 + l4 * 4;
    const int ccol0 = bn * 128 + wc * 64 + l15;
    float bias4[4];
    #pragma unroll
    for (int n = 0; n < 4; n++) bias4[n] = bias[ccol0 + n * 16];
    #pragma unroll
    for (int m = 0; m < 4; m++)
        #pragma unroll
        for (int j = 0; j < 4; j++) {
            const long r = crow0 + m * 16 + j;
            float* crow = C + r * N;
            const float* rrow = resid + r * N;
            #pragma unroll
            for (int n = 0; n < 4; n++) {
                const int col = ccol0 + n * 16;
                crow[col] = acc[m][n][j] + bias4[n] + rrow[col];
            }
        }
}

extern "C" void kernel_launch(void* const* d_in, const int* in_sizes, int n_in,
                              void* d_out, int out_size, void* d_ws, size_t ws_size,
                              hipStream_t stream) {
    // setup_inputs order: x, w_q, b_q, w_k, b_k, w_v, b_v, w_o, b_o, ln_gamma, ln_beta
    const float* x     = (const float*)d_in[0];
    const float* w_v   = (const float*)d_in[5];
    const float* b_v   = (const float*)d_in[6];
    const float* w_o   = (const float*)d_in[7];
    const float* b_o   = (const float*)d_in[8];
    const float* gamma = (const float*)d_in[9];
    const float* beta  = (const float*)d_in[10];
    float* out = (float*)d_out;

    char* ws = (char*)d_ws;
    unsigned short* h   = (unsigned short*)(ws);                              // 64 MiB
    unsigned short* wvT = (unsigned short*)(ws + 67108864L);                  // 8 MiB
    unsigned short* woB = (unsigned short*)(ws + 67108864L + 8388608L);       // 8 MiB
    unsigned short* Wc  = (unsigned short*)(ws + 67108864L + 2 * 8388608L);   // 8 MiB
    float*          b_c = (float*)(ws + 67108864L + 3 * 8388608L);            // 8 KiB

    // K1: transpose(w_v) || convert(w_o) || bias-combine
    prep_kernel<<<8192, 256, 0, stream>>>(w_v, w_o, b_v, b_o, wvT, woB, b_c);
    // K2: Wc = woB . wvT^T (blocks 0-255) || h = LN(x) (blocks 256+)
    lnwc_kernel<<<256 + N_BATCH, 256, 0, stream>>>(woB, wvT, Wc, x, gamma, beta, h);
    // K3: out = h . Wc^T + b_c + x
    gemm_bt_128r<<<(N_BATCH / 128) * (D_MODEL / 128), 256, 0, stream>>>(
        h, Wc, out, b_c, x, N_BATCH, D_MODEL, D_MODEL);
}